// Round 4
// baseline (99.739 us; speedup 1.0000x reference)
//
#include <hip/hip_runtime.h>

#define NV 100000
#define NJ 24
#define NP 207
#define NPART 25

// ---------------------------------------------------------------------------
// K1: v_shaped = v_template + shapedirs @ betas, flat over 300000 rows of 10.
// ---------------------------------------------------------------------------
__global__ __launch_bounds__(256) void k_shape(
    const float* __restrict__ betas, const float* __restrict__ v_template,
    const float* __restrict__ shapedirs, float* __restrict__ v_shaped) {
  __shared__ float sb[10];
  if (threadIdx.x < 10) sb[threadIdx.x] = betas[threadIdx.x];
  __syncthreads();
  int R = blockIdx.x * 256 + threadIdx.x;
  if (R >= 3 * NV) return;
  const float2* sd = (const float2*)(shapedirs + (size_t)R * 10);
  float a = v_template[R];
  #pragma unroll
  for (int s = 0; s < 5; ++s) {
    float2 x = sd[s];
    a += x.x * sb[2 * s] + x.y * sb[2 * s + 1];
  }
  v_shaped[R] = a;
}

// ---------------------------------------------------------------------------
// K2: J partials.  grid = (24 joints, 25 parts), pure float4 loads.
// verts per slice = 4000 -> 1000 float4 of Jreg, 3000 float4 of v_shaped.
// ---------------------------------------------------------------------------
__global__ __launch_bounds__(256) void k_jreg(
    const float* __restrict__ Jreg, const float* __restrict__ v_shaped,
    float* __restrict__ jpart) {
  int j = blockIdx.x, part = blockIdx.y, tid = threadIdx.x;
  const int SL = NV / NPART;  // 4000
  int v0 = part * SL;
  const float4* w4 = (const float4*)(Jreg + (size_t)j * NV + v0);
  const float4* s4 = (const float4*)(v_shaped + (size_t)3 * v0);
  float s0 = 0.f, s1 = 0.f, s2 = 0.f;
  for (int i4 = tid; i4 < SL / 4; i4 += 256) {
    float4 w = w4[i4];
    float4 A = s4[3 * i4 + 0];
    float4 B = s4[3 * i4 + 1];
    float4 C = s4[3 * i4 + 2];
    s0 += w.x * A.x + w.y * A.w + w.z * B.z + w.w * C.y;
    s1 += w.x * A.y + w.y * B.x + w.z * B.w + w.w * C.z;
    s2 += w.x * A.z + w.y * B.y + w.z * C.x + w.w * C.w;
  }
  __shared__ float red[256][3];
  red[tid][0] = s0; red[tid][1] = s1; red[tid][2] = s2;
  __syncthreads();
  for (int off = 128; off > 0; off >>= 1) {
    if (tid < off) {
      red[tid][0] += red[tid + off][0];
      red[tid][1] += red[tid + off][1];
      red[tid][2] += red[tid + off][2];
    }
    __syncthreads();
  }
  if (tid < 3) jpart[(part * NJ + j) * 3 + tid] = red[0][tid];
}

// ---------------------------------------------------------------------------
// K3: single block: finalize J, rodrigues, FK chain, rel matrices, lrotmin
// ---------------------------------------------------------------------------
__global__ __launch_bounds__(64) void k_fk(
    const float* __restrict__ pose, const float* __restrict__ jpart,
    float* __restrict__ lrot, float* __restrict__ rel) {
  __shared__ float J[NJ][3];
  __shared__ float R[NJ][9];
  __shared__ float G[NJ][12];
  int tid = threadIdx.x;
  if (tid < NJ) {
    for (int k = 0; k < 3; ++k) {
      float a = 0.f;
      for (int part = 0; part < NPART; ++part) a += jpart[(part * NJ + tid) * 3 + k];
      J[tid][k] = a;
    }
    float rx = pose[tid * 3 + 0], ry = pose[tid * 3 + 1], rz = pose[tid * 3 + 2];
    float tx = rx + 1e-8f, ty = ry + 1e-8f, tz = rz + 1e-8f;
    float theta = sqrtf(tx * tx + ty * ty + tz * tz);
    float x = rx / theta, y = ry / theta, z = rz / theta;
    float c = cosf(theta), s = sinf(theta), C = 1.f - c;
    float* Rr = R[tid];
    Rr[0] = c + C * x * x;     Rr[1] = C * x * y - s * z; Rr[2] = C * x * z + s * y;
    Rr[3] = C * x * y + s * z; Rr[4] = c + C * y * y;     Rr[5] = C * y * z - s * x;
    Rr[6] = C * x * z - s * y; Rr[7] = C * y * z + s * x; Rr[8] = c + C * z * z;
    if (tid >= 1) {
      #pragma unroll
      for (int e = 0; e < 9; ++e) {
        float id = (e == 0 || e == 4 || e == 8) ? 1.f : 0.f;
        lrot[(tid - 1) * 9 + e] = Rr[e] - id;
      }
    }
  }
  __syncthreads();
  if (tid == 0) {
    const int par[NJ] = {-1,0,0,0,1,2,3,4,5,6,7,8,9,9,9,12,13,14,16,17,18,19,20,21};
    for (int a = 0; a < 3; ++a) {
      for (int b = 0; b < 3; ++b) G[0][a * 4 + b] = R[0][a * 3 + b];
      G[0][a * 4 + 3] = J[0][a];
    }
    for (int i = 1; i < NJ; ++i) {
      int p = par[i];
      float t0 = J[i][0] - J[p][0], t1 = J[i][1] - J[p][1], t2 = J[i][2] - J[p][2];
      for (int a = 0; a < 3; ++a) {
        float g0 = G[p][a * 4 + 0], g1 = G[p][a * 4 + 1], g2 = G[p][a * 4 + 2];
        for (int b = 0; b < 3; ++b)
          G[i][a * 4 + b] = g0 * R[i][0 * 3 + b] + g1 * R[i][1 * 3 + b] + g2 * R[i][2 * 3 + b];
        G[i][a * 4 + 3] = G[p][a * 4 + 3] + g0 * t0 + g1 * t1 + g2 * t2;
      }
    }
  }
  __syncthreads();
  if (tid < NJ) {
    for (int a = 0; a < 3; ++a) {
      float corr = G[tid][a * 4 + 0] * J[tid][0] + G[tid][a * 4 + 1] * J[tid][1] +
                   G[tid][a * 4 + 2] * J[tid][2];
      rel[tid * 12 + a * 4 + 0] = G[tid][a * 4 + 0];
      rel[tid * 12 + a * 4 + 1] = G[tid][a * 4 + 1];
      rel[tid * 12 + a * 4 + 2] = G[tid][a * 4 + 2];
      rel[tid * 12 + a * 4 + 3] = G[tid][a * 4 + 3] - corr;
    }
  }
}

// ---------------------------------------------------------------------------
// K4: fused pose-blend + LBS. 16 threads per vertex, 16 verts per block.
// Each thread streams its vertex's posedirs row directly from global as
// ALIGNED float4s: window starts at 621*v - (v&3) (multiple of 4 floats);
// the phase shift is folded into 4 pre-shifted weight tables T[k][s][m] in
// LDS (T = lrotmin value or 0 for out-of-row/garbage elements). Masking
// f4<=155 guarantees no OOB read (last vertex has phase 3).
// Then shfl_xor reduce -> delta in LDS -> 16 threads do LBS + scale/trans.
// ---------------------------------------------------------------------------
__global__ __launch_bounds__(256) void k_fused(
    const float* __restrict__ posedirs, const float* __restrict__ weights,
    const float* __restrict__ lrot, const float* __restrict__ rel,
    const float* __restrict__ scale, const float* __restrict__ trans,
    float* __restrict__ vbuf) {
  __shared__ float T[3][4][640];
  __shared__ float rl[NJ * 12];
  __shared__ float lrs[NP];
  __shared__ float delta[16][3];
  int tid = threadIdx.x;
  if (tid < NP) lrs[tid] = lrot[tid];
  for (int i = tid; i < NJ * 12; i += 256) rl[i] = rel[i];
  __syncthreads();
  for (int t = tid; t < 3 * 4 * 640; t += 256) {
    int k = t / 2560;
    int r = t - k * 2560;
    int s = r / 640;
    int m = r - s * 640;
    int e = m - s;
    int lo = 207 * k;
    T[k][s][m] = (e >= lo && e < lo + 207) ? lrs[e - lo] : 0.f;
  }
  __syncthreads();

  int lv = tid >> 4, sub = tid & 15;
  int v = blockIdx.x * 16 + lv;
  int s = v & 3;
  size_t base = (size_t)v * 621 - s;  // multiple of 4 floats -> 16B aligned
  const float4* pv4 = (const float4*)(posedirs + base);
  float4 x[10];
  #pragma unroll
  for (int it = 0; it < 10; ++it) {
    int f4 = sub + 16 * it;
    if (f4 <= 155) x[it] = pv4[f4];
    else x[it] = make_float4(0.f, 0.f, 0.f, 0.f);
  }
  float a0 = 0.f, a1 = 0.f, a2 = 0.f;
  #pragma unroll
  for (int it = 0; it < 10; ++it) {
    int f4 = sub + 16 * it;
    if (f4 <= 155) {
      float4 t0 = *(const float4*)&T[0][s][4 * f4];
      float4 t1 = *(const float4*)&T[1][s][4 * f4];
      float4 t2 = *(const float4*)&T[2][s][4 * f4];
      float4 xv = x[it];
      a0 += xv.x * t0.x + xv.y * t0.y + xv.z * t0.z + xv.w * t0.w;
      a1 += xv.x * t1.x + xv.y * t1.y + xv.z * t1.z + xv.w * t1.w;
      a2 += xv.x * t2.x + xv.y * t2.y + xv.z * t2.z + xv.w * t2.w;
    }
  }
  #pragma unroll
  for (int off = 8; off > 0; off >>= 1) {
    a0 += __shfl_xor(a0, off);
    a1 += __shfl_xor(a1, off);
    a2 += __shfl_xor(a2, off);
  }
  if (sub == 0) {
    delta[lv][0] = a0; delta[lv][1] = a1; delta[lv][2] = a2;
  }
  __syncthreads();
  if (tid < 16) {
    int vv = blockIdx.x * 16 + tid;
    float p0 = vbuf[3 * vv + 0] + delta[tid][0];
    float p1 = vbuf[3 * vv + 1] + delta[tid][1];
    float p2 = vbuf[3 * vv + 2] + delta[tid][2];
    float4 w4[6];
    const float4* wv = (const float4*)(weights + (size_t)vv * NJ);
    #pragma unroll
    for (int i = 0; i < 6; ++i) w4[i] = wv[i];
    const float* w = (const float*)w4;
    float Tm[12];
    #pragma unroll
    for (int e = 0; e < 12; ++e) Tm[e] = 0.f;
    #pragma unroll
    for (int j = 0; j < NJ; ++j) {
      float wj = w[j];
      #pragma unroll
      for (int e = 0; e < 12; ++e) Tm[e] += wj * rl[j * 12 + e];
    }
    float sc = scale[0];
    float o0 = Tm[0] * p0 + Tm[1] * p1 + Tm[2]  * p2 + Tm[3];
    float o1 = Tm[4] * p0 + Tm[5] * p1 + Tm[6]  * p2 + Tm[7];
    float o2 = Tm[8] * p0 + Tm[9] * p1 + Tm[10] * p2 + Tm[11];
    vbuf[3 * vv + 0] = o0 * sc + trans[0];
    vbuf[3 * vv + 1] = o1 * sc + trans[1];
    vbuf[3 * vv + 2] = o2 * sc + trans[2];
  }
}

extern "C" void kernel_launch(void* const* d_in, const int* in_sizes, int n_in,
                              void* d_out, int out_size, void* d_ws, size_t ws_size,
                              hipStream_t stream) {
  const float* betas      = (const float*)d_in[0];
  const float* pose       = (const float*)d_in[1];
  const float* scale      = (const float*)d_in[2];
  const float* trans      = (const float*)d_in[3];
  const float* v_template = (const float*)d_in[4];
  const float* shapedirs  = (const float*)d_in[5];
  const float* posedirs   = (const float*)d_in[6];
  const float* Jreg       = (const float*)d_in[7];
  const float* weights    = (const float*)d_in[8];
  float* out = (float*)d_out;
  float* ws  = (float*)d_ws;

  float* jpart = ws;          // 25*24*3 = 1800 floats
  float* lrot  = ws + 1800;   // 207 floats
  float* rel   = ws + 2048;   // 288 floats

  k_shape<<<(3 * NV + 255) / 256, 256, 0, stream>>>(betas, v_template, shapedirs, out);
  k_jreg<<<dim3(NJ, NPART), 256, 0, stream>>>(Jreg, out, jpart);
  k_fk<<<1, 64, 0, stream>>>(pose, jpart, lrot, rel);
  k_fused<<<NV / 16, 256, 0, stream>>>(posedirs, weights, lrot, rel, scale, trans, out);
}

// Round 5
// 77.324 us; speedup vs baseline: 1.2899x; 1.2899x over previous
//
#include <hip/hip_runtime.h>

#define NV 100000
#define NJ 24
#define NP 207
#define NPART 25
#define VPB 8                  // vertices per block in fused kernel
#define TF (VPB * 3 * NP)      // 4968 floats per block tile
#define TF4 (TF / 4)           // 1242 float4 per tile

// ---------------------------------------------------------------------------
// K1: v_shaped = v_template + shapedirs @ betas, flat over 300000 rows of 10.
// ---------------------------------------------------------------------------
__global__ __launch_bounds__(256) void k_shape(
    const float* __restrict__ betas, const float* __restrict__ v_template,
    const float* __restrict__ shapedirs, float* __restrict__ v_shaped) {
  __shared__ float sb[10];
  if (threadIdx.x < 10) sb[threadIdx.x] = betas[threadIdx.x];
  __syncthreads();
  int R = blockIdx.x * 256 + threadIdx.x;
  if (R >= 3 * NV) return;
  const float2* sd = (const float2*)(shapedirs + (size_t)R * 10);
  float a = v_template[R];
  #pragma unroll
  for (int s = 0; s < 5; ++s) {
    float2 x = sd[s];
    a += x.x * sb[2 * s] + x.y * sb[2 * s + 1];
  }
  v_shaped[R] = a;
}

// ---------------------------------------------------------------------------
// K2: J partials.  grid = (24 joints, 25 parts), pure float4 loads.
// ---------------------------------------------------------------------------
__global__ __launch_bounds__(256) void k_jreg(
    const float* __restrict__ Jreg, const float* __restrict__ v_shaped,
    float* __restrict__ jpart) {
  int j = blockIdx.x, part = blockIdx.y, tid = threadIdx.x;
  const int SL = NV / NPART;  // 4000
  int v0 = part * SL;
  const float4* w4 = (const float4*)(Jreg + (size_t)j * NV + v0);
  const float4* s4 = (const float4*)(v_shaped + (size_t)3 * v0);
  float s0 = 0.f, s1 = 0.f, s2 = 0.f;
  for (int i4 = tid; i4 < SL / 4; i4 += 256) {
    float4 w = w4[i4];
    float4 A = s4[3 * i4 + 0];
    float4 B = s4[3 * i4 + 1];
    float4 C = s4[3 * i4 + 2];
    s0 += w.x * A.x + w.y * A.w + w.z * B.z + w.w * C.y;
    s1 += w.x * A.y + w.y * B.x + w.z * B.w + w.w * C.z;
    s2 += w.x * A.z + w.y * B.y + w.z * C.x + w.w * C.w;
  }
  __shared__ float red[256][3];
  red[tid][0] = s0; red[tid][1] = s1; red[tid][2] = s2;
  __syncthreads();
  for (int off = 128; off > 0; off >>= 1) {
    if (tid < off) {
      red[tid][0] += red[tid + off][0];
      red[tid][1] += red[tid + off][1];
      red[tid][2] += red[tid + off][2];
    }
    __syncthreads();
  }
  if (tid < 3) jpart[(part * NJ + j) * 3 + tid] = red[0][tid];
}

// ---------------------------------------------------------------------------
// K3: single block: finalize J, rodrigues, FK chain, rel matrices, lrotmin
// ---------------------------------------------------------------------------
__global__ __launch_bounds__(64) void k_fk(
    const float* __restrict__ pose, const float* __restrict__ jpart,
    float* __restrict__ lrot, float* __restrict__ rel) {
  __shared__ float J[NJ][3];
  __shared__ float R[NJ][9];
  __shared__ float G[NJ][12];
  int tid = threadIdx.x;
  if (tid < NJ) {
    for (int k = 0; k < 3; ++k) {
      float a = 0.f;
      for (int part = 0; part < NPART; ++part) a += jpart[(part * NJ + tid) * 3 + k];
      J[tid][k] = a;
    }
    float rx = pose[tid * 3 + 0], ry = pose[tid * 3 + 1], rz = pose[tid * 3 + 2];
    float tx = rx + 1e-8f, ty = ry + 1e-8f, tz = rz + 1e-8f;
    float theta = sqrtf(tx * tx + ty * ty + tz * tz);
    float x = rx / theta, y = ry / theta, z = rz / theta;
    float c = cosf(theta), s = sinf(theta), C = 1.f - c;
    float* Rr = R[tid];
    Rr[0] = c + C * x * x;     Rr[1] = C * x * y - s * z; Rr[2] = C * x * z + s * y;
    Rr[3] = C * x * y + s * z; Rr[4] = c + C * y * y;     Rr[5] = C * y * z - s * x;
    Rr[6] = C * x * z - s * y; Rr[7] = C * y * z + s * x; Rr[8] = c + C * z * z;
    if (tid >= 1) {
      #pragma unroll
      for (int e = 0; e < 9; ++e) {
        float id = (e == 0 || e == 4 || e == 8) ? 1.f : 0.f;
        lrot[(tid - 1) * 9 + e] = Rr[e] - id;
      }
    }
  }
  __syncthreads();
  if (tid == 0) {
    const int par[NJ] = {-1,0,0,0,1,2,3,4,5,6,7,8,9,9,9,12,13,14,16,17,18,19,20,21};
    for (int a = 0; a < 3; ++a) {
      for (int b = 0; b < 3; ++b) G[0][a * 4 + b] = R[0][a * 3 + b];
      G[0][a * 4 + 3] = J[0][a];
    }
    for (int i = 1; i < NJ; ++i) {
      int p = par[i];
      float t0 = J[i][0] - J[p][0], t1 = J[i][1] - J[p][1], t2 = J[i][2] - J[p][2];
      for (int a = 0; a < 3; ++a) {
        float g0 = G[p][a * 4 + 0], g1 = G[p][a * 4 + 1], g2 = G[p][a * 4 + 2];
        for (int b = 0; b < 3; ++b)
          G[i][a * 4 + b] = g0 * R[i][0 * 3 + b] + g1 * R[i][1 * 3 + b] + g2 * R[i][2 * 3 + b];
        G[i][a * 4 + 3] = G[p][a * 4 + 3] + g0 * t0 + g1 * t1 + g2 * t2;
      }
    }
  }
  __syncthreads();
  if (tid < NJ) {
    for (int a = 0; a < 3; ++a) {
      float corr = G[tid][a * 4 + 0] * J[tid][0] + G[tid][a * 4 + 1] * J[tid][1] +
                   G[tid][a * 4 + 2] * J[tid][2];
      rel[tid * 12 + a * 4 + 0] = G[tid][a * 4 + 0];
      rel[tid * 12 + a * 4 + 1] = G[tid][a * 4 + 1];
      rel[tid * 12 + a * 4 + 2] = G[tid][a * 4 + 2];
      rel[tid * 12 + a * 4 + 3] = G[tid][a * 4 + 3] - corr;
    }
  }
}

// ---------------------------------------------------------------------------
// K4: fused pose-blend + LBS. Block owns 8 vertices = one contiguous,
// 16B-aligned 19872B slab, DMA'd to LDS via global_load_lds (width 16,
// linear dest). Phase B: 32 threads/vertex scalar-dot from LDS (row stride
// 621 = 13 mod 32 -> <=2-way bank alias = free), 5-round shfl_xor reduce,
// then 8 threads finish LBS + scale/trans. One kernel, no vbuf RMW.
// ---------------------------------------------------------------------------
__global__ __launch_bounds__(256) void k_fused(
    const float* __restrict__ posedirs, const float* __restrict__ weights,
    const float* __restrict__ lrot, const float* __restrict__ rel,
    const float* __restrict__ scale, const float* __restrict__ trans,
    float* __restrict__ vbuf) {
  __shared__ float tile[TF];
  __shared__ float lrs[NP];
  __shared__ float rl[NJ * 12];
  __shared__ float delta[VPB][3];
  int tid = threadIdx.x;

  // Phase A: DMA the block's posedirs slab into LDS, linear, width-16.
  const float4* src4 = (const float4*)posedirs + (size_t)blockIdx.x * TF4;
  float4* tile4 = (float4*)tile;
  int wbase = tid & 192;  // wave-uniform base offset (in float4 slots)
  #pragma unroll
  for (int it = 0; it < 5; ++it) {
    int i4 = 256 * it + tid;
    if (i4 < TF4) {
      __builtin_amdgcn_global_load_lds(
          (const __attribute__((address_space(1))) void*)(src4 + i4),
          (__attribute__((address_space(3))) void*)(tile4 + 256 * it + wbase),
          16, 0, 0);
    }
  }
  if (tid < NP) lrs[tid] = lrot[tid];
  for (int i = tid; i < NJ * 12; i += 256) rl[i] = rel[i];
  __syncthreads();

  // Phase B: 32 threads per vertex dot 3x207 from LDS.
  int lv = tid >> 5, sub = tid & 31;
  const float* row = tile + lv * (3 * NP);
  float a0 = 0.f, a1 = 0.f, a2 = 0.f;
  #pragma unroll
  for (int e = 0; e < 7; ++e) {
    int p = sub + 32 * e;
    if (p < NP) {
      float l = lrs[p];
      a0 += row[p] * l;
      a1 += row[NP + p] * l;
      a2 += row[2 * NP + p] * l;
    }
  }
  #pragma unroll
  for (int off = 16; off > 0; off >>= 1) {
    a0 += __shfl_xor(a0, off);
    a1 += __shfl_xor(a1, off);
    a2 += __shfl_xor(a2, off);
  }
  if (sub == 0) {
    delta[lv][0] = a0; delta[lv][1] = a1; delta[lv][2] = a2;
  }
  __syncthreads();

  // Phase C: LBS + scale/trans for the block's 8 vertices.
  if (tid < VPB) {
    int vv = blockIdx.x * VPB + tid;
    float p0 = vbuf[3 * vv + 0] + delta[tid][0];
    float p1 = vbuf[3 * vv + 1] + delta[tid][1];
    float p2 = vbuf[3 * vv + 2] + delta[tid][2];
    float4 w4[6];
    const float4* wv = (const float4*)(weights + (size_t)vv * NJ);
    #pragma unroll
    for (int i = 0; i < 6; ++i) w4[i] = wv[i];
    const float* w = (const float*)w4;
    float Tm[12];
    #pragma unroll
    for (int e = 0; e < 12; ++e) Tm[e] = 0.f;
    #pragma unroll
    for (int j = 0; j < NJ; ++j) {
      float wj = w[j];
      #pragma unroll
      for (int e = 0; e < 12; ++e) Tm[e] += wj * rl[j * 12 + e];
    }
    float sc = scale[0];
    float o0 = Tm[0] * p0 + Tm[1] * p1 + Tm[2]  * p2 + Tm[3];
    float o1 = Tm[4] * p0 + Tm[5] * p1 + Tm[6]  * p2 + Tm[7];
    float o2 = Tm[8] * p0 + Tm[9] * p1 + Tm[10] * p2 + Tm[11];
    vbuf[3 * vv + 0] = o0 * sc + trans[0];
    vbuf[3 * vv + 1] = o1 * sc + trans[1];
    vbuf[3 * vv + 2] = o2 * sc + trans[2];
  }
}

extern "C" void kernel_launch(void* const* d_in, const int* in_sizes, int n_in,
                              void* d_out, int out_size, void* d_ws, size_t ws_size,
                              hipStream_t stream) {
  const float* betas      = (const float*)d_in[0];
  const float* pose       = (const float*)d_in[1];
  const float* scale      = (const float*)d_in[2];
  const float* trans      = (const float*)d_in[3];
  const float* v_template = (const float*)d_in[4];
  const float* shapedirs  = (const float*)d_in[5];
  const float* posedirs   = (const float*)d_in[6];
  const float* Jreg       = (const float*)d_in[7];
  const float* weights    = (const float*)d_in[8];
  float* out = (float*)d_out;
  float* ws  = (float*)d_ws;

  float* jpart = ws;          // 25*24*3 = 1800 floats
  float* lrot  = ws + 1800;   // 207 floats
  float* rel   = ws + 2048;   // 288 floats

  k_shape<<<(3 * NV + 255) / 256, 256, 0, stream>>>(betas, v_template, shapedirs, out);
  k_jreg<<<dim3(NJ, NPART), 256, 0, stream>>>(Jreg, out, jpart);
  k_fk<<<1, 64, 0, stream>>>(pose, jpart, lrot, rel);
  k_fused<<<NV / VPB, 256, 0, stream>>>(posedirs, weights, lrot, rel, scale, trans, out);
}

// Round 6
// 68.265 us; speedup vs baseline: 1.4610x; 1.1327x over previous
//
#include <hip/hip_runtime.h>

#define NV 100000
#define NJ 24
#define NP 207
#define NPART 25
#define VPB 8
#define NTILES (NV / VPB)      // 12500
#define TF4 1242               // float4 per tile = VPB*621/4
#define GRIDF 1024             // persistent grid (4 blocks/CU * 256 CU)

// ---------------------------------------------------------------------------
// K1: v_shaped = v_template + shapedirs @ betas, flat over 300000 rows of 10.
// ---------------------------------------------------------------------------
__global__ __launch_bounds__(256) void k_shape(
    const float* __restrict__ betas, const float* __restrict__ v_template,
    const float* __restrict__ shapedirs, float* __restrict__ v_shaped) {
  __shared__ float sb[10];
  if (threadIdx.x < 10) sb[threadIdx.x] = betas[threadIdx.x];
  __syncthreads();
  int R = blockIdx.x * 256 + threadIdx.x;
  if (R >= 3 * NV) return;
  const float2* sd = (const float2*)(shapedirs + (size_t)R * 10);
  float a = v_template[R];
  #pragma unroll
  for (int s = 0; s < 5; ++s) {
    float2 x = sd[s];
    a += x.x * sb[2 * s] + x.y * sb[2 * s + 1];
  }
  v_shaped[R] = a;
}

// ---------------------------------------------------------------------------
// K2: J partials.  grid = (24 joints, 25 parts), pure float4 loads.
// ---------------------------------------------------------------------------
__global__ __launch_bounds__(256) void k_jreg(
    const float* __restrict__ Jreg, const float* __restrict__ v_shaped,
    float* __restrict__ jpart) {
  int j = blockIdx.x, part = blockIdx.y, tid = threadIdx.x;
  const int SL = NV / NPART;  // 4000
  int v0 = part * SL;
  const float4* w4 = (const float4*)(Jreg + (size_t)j * NV + v0);
  const float4* s4 = (const float4*)(v_shaped + (size_t)3 * v0);
  float s0 = 0.f, s1 = 0.f, s2 = 0.f;
  for (int i4 = tid; i4 < SL / 4; i4 += 256) {
    float4 w = w4[i4];
    float4 A = s4[3 * i4 + 0];
    float4 B = s4[3 * i4 + 1];
    float4 C = s4[3 * i4 + 2];
    s0 += w.x * A.x + w.y * A.w + w.z * B.z + w.w * C.y;
    s1 += w.x * A.y + w.y * B.x + w.z * B.w + w.w * C.z;
    s2 += w.x * A.z + w.y * B.y + w.z * C.x + w.w * C.w;
  }
  __shared__ float red[256][3];
  red[tid][0] = s0; red[tid][1] = s1; red[tid][2] = s2;
  __syncthreads();
  for (int off = 128; off > 0; off >>= 1) {
    if (tid < off) {
      red[tid][0] += red[tid + off][0];
      red[tid][1] += red[tid + off][1];
      red[tid][2] += red[tid + off][2];
    }
    __syncthreads();
  }
  if (tid < 3) jpart[(part * NJ + j) * 3 + tid] = red[0][tid];
}

// ---------------------------------------------------------------------------
// K3: single block: finalize J, rodrigues, FK chain, rel matrices, lrotmin
// ---------------------------------------------------------------------------
__global__ __launch_bounds__(64) void k_fk(
    const float* __restrict__ pose, const float* __restrict__ jpart,
    float* __restrict__ lrot, float* __restrict__ rel) {
  __shared__ float J[NJ][3];
  __shared__ float R[NJ][9];
  __shared__ float G[NJ][12];
  int tid = threadIdx.x;
  if (tid < NJ) {
    for (int k = 0; k < 3; ++k) {
      float a = 0.f;
      for (int part = 0; part < NPART; ++part) a += jpart[(part * NJ + tid) * 3 + k];
      J[tid][k] = a;
    }
    float rx = pose[tid * 3 + 0], ry = pose[tid * 3 + 1], rz = pose[tid * 3 + 2];
    float tx = rx + 1e-8f, ty = ry + 1e-8f, tz = rz + 1e-8f;
    float theta = sqrtf(tx * tx + ty * ty + tz * tz);
    float x = rx / theta, y = ry / theta, z = rz / theta;
    float c = cosf(theta), s = sinf(theta), C = 1.f - c;
    float* Rr = R[tid];
    Rr[0] = c + C * x * x;     Rr[1] = C * x * y - s * z; Rr[2] = C * x * z + s * y;
    Rr[3] = C * x * y + s * z; Rr[4] = c + C * y * y;     Rr[5] = C * y * z - s * x;
    Rr[6] = C * x * z - s * y; Rr[7] = C * y * z + s * x; Rr[8] = c + C * z * z;
    if (tid >= 1) {
      #pragma unroll
      for (int e = 0; e < 9; ++e) {
        float id = (e == 0 || e == 4 || e == 8) ? 1.f : 0.f;
        lrot[(tid - 1) * 9 + e] = Rr[e] - id;
      }
    }
  }
  __syncthreads();
  if (tid == 0) {
    const int par[NJ] = {-1,0,0,0,1,2,3,4,5,6,7,8,9,9,9,12,13,14,16,17,18,19,20,21};
    for (int a = 0; a < 3; ++a) {
      for (int b = 0; b < 3; ++b) G[0][a * 4 + b] = R[0][a * 3 + b];
      G[0][a * 4 + 3] = J[0][a];
    }
    for (int i = 1; i < NJ; ++i) {
      int p = par[i];
      float t0 = J[i][0] - J[p][0], t1 = J[i][1] - J[p][1], t2 = J[i][2] - J[p][2];
      for (int a = 0; a < 3; ++a) {
        float g0 = G[p][a * 4 + 0], g1 = G[p][a * 4 + 1], g2 = G[p][a * 4 + 2];
        for (int b = 0; b < 3; ++b)
          G[i][a * 4 + b] = g0 * R[i][0 * 3 + b] + g1 * R[i][1 * 3 + b] + g2 * R[i][2 * 3 + b];
        G[i][a * 4 + 3] = G[p][a * 4 + 3] + g0 * t0 + g1 * t1 + g2 * t2;
      }
    }
  }
  __syncthreads();
  if (tid < NJ) {
    for (int a = 0; a < 3; ++a) {
      float corr = G[tid][a * 4 + 0] * J[tid][0] + G[tid][a * 4 + 1] * J[tid][1] +
                   G[tid][a * 4 + 2] * J[tid][2];
      rel[tid * 12 + a * 4 + 0] = G[tid][a * 4 + 0];
      rel[tid * 12 + a * 4 + 1] = G[tid][a * 4 + 1];
      rel[tid * 12 + a * 4 + 2] = G[tid][a * 4 + 2];
      rel[tid * 12 + a * 4 + 3] = G[tid][a * 4 + 3] - corr;
    }
  }
}

// ---------------------------------------------------------------------------
// Stage one 8-vertex posedirs tile (1242 float4) into LDS via DMA.
// Every wave issues exactly 5 global_load_lds (round 4 is exec-masked but
// nonzero for all 4 waves) -> uniform vmcnt accounting.
// ---------------------------------------------------------------------------
__device__ __forceinline__ void stage_tile(float4* dst, const float4* src, int tid) {
  #pragma unroll
  for (int r = 0; r < 5; ++r) {
    int i4 = r * 256 + tid;
    if (i4 < TF4) {
      __builtin_amdgcn_global_load_lds(
          (const __attribute__((address_space(1))) void*)(src + i4),
          (__attribute__((address_space(3))) void*)(dst + r * 256 + (tid & 192)),
          16, 0, 0);
    }
  }
}

// ---------------------------------------------------------------------------
// K4: persistent fused pose-blend + LBS, double-buffered counted-vmcnt
// pipeline. Wave = 2 vertices (32 lanes each). lrotmin/rel live in registers.
// Per iter: [W load][5x DMA next tile][vmcnt(5)][barrier][compute][barrier].
// vmcnt(5) guarantees (in-order completion) everything older than the 5 new
// DMAs -- i.e. the current tile -- has landed, while next tile stays in flight.
// ---------------------------------------------------------------------------
__global__ __launch_bounds__(256, 4) void k_fused(
    const float* __restrict__ posedirs, const float* __restrict__ weights,
    const float* __restrict__ lrot, const float* __restrict__ rel,
    const float* __restrict__ scale, const float* __restrict__ trans,
    float* __restrict__ vbuf) {
  __shared__ float4 tile[2][TF4];
  int tid = threadIdx.x;
  int wid = tid >> 6, lane = tid & 63, half = lane >> 5, lj = lane & 31;

  int t0 = blockIdx.x;
  const float4* pd4 = (const float4*)posedirs;
  // prologue: stage tile t0 into buffer 0 (overlaps constant loads below)
  stage_tile(&tile[0][0], pd4 + (size_t)t0 * TF4, tid);

  // per-lane constants (zero-filled on inactive lanes: avoid NaN*0)
  float llr[7];
  #pragma unroll
  for (int e = 0; e < 7; ++e) {
    int p = lj + 32 * e;
    llr[e] = (p < NP) ? lrot[p] : 0.f;
  }
  float rlq[12];
  #pragma unroll
  for (int e = 0; e < 12; ++e) rlq[e] = (lj < NJ) ? rel[lj * 12 + e] : 0.f;
  float sc = scale[0];
  float tr = (lj < 3) ? trans[lj] : 0.f;

  int nt = (NTILES - 1 - t0) / GRIDF + 1;
  __syncthreads();  // drains prologue DMA (vmcnt 0) + aligns waves

  for (int it = 0; it < nt; ++it) {
    int cur = it & 1;
    int tcur = t0 + it * GRIDF;
    int vv = tcur * VPB + (wid << 1) + half;
    float wj = (lj < NJ) ? weights[(size_t)vv * NJ + lj] : 0.f;
    int tnext = t0 + (it + 1) * GRIDF;
    if (tnext >= NTILES) tnext = NTILES - 1;  // dummy on last iter: keeps counts uniform
    stage_tile(&tile[cur ^ 1][0], pd4 + (size_t)tnext * TF4, tid);
    asm volatile("s_waitcnt vmcnt(5)" ::: "memory");
    __builtin_amdgcn_sched_barrier(0);
    __builtin_amdgcn_s_barrier();
    __builtin_amdgcn_sched_barrier(0);

    float pvl = (lj < 3) ? vbuf[(size_t)3 * vv + lj] : 0.f;  // v_shaped, early

    const float* row = (const float*)&tile[cur][0] + ((wid << 1) + half) * (3 * NP);
    float a0 = 0.f, a1 = 0.f, a2 = 0.f;
    #pragma unroll
    for (int e = 0; e < 7; ++e) {
      int p = lj + 32 * e;
      if (p < NP) {
        float l = llr[e];
        a0 += row[p] * l;
        a1 += row[NP + p] * l;
        a2 += row[2 * NP + p] * l;
      }
    }
    #pragma unroll
    for (int off = 16; off > 0; off >>= 1) {
      a0 += __shfl_xor(a0, off);
      a1 += __shfl_xor(a1, off);
      a2 += __shfl_xor(a2, off);
    }
    int gb = lane & 32;
    float p0 = __shfl(pvl, gb + 0) + a0;
    float p1 = __shfl(pvl, gb + 1) + a1;
    float p2 = __shfl(pvl, gb + 2) + a2;
    // lane j<24: w_j * (rel_j . [p,1]), reduce over the 32-lane group
    float q0 = rlq[0] * p0 + rlq[1] * p1 + rlq[2]  * p2 + rlq[3];
    float q1 = rlq[4] * p0 + rlq[5] * p1 + rlq[6]  * p2 + rlq[7];
    float q2 = rlq[8] * p0 + rlq[9] * p1 + rlq[10] * p2 + rlq[11];
    float r0 = wj * q0, r1 = wj * q1, r2 = wj * q2;
    #pragma unroll
    for (int off = 16; off > 0; off >>= 1) {
      r0 += __shfl_xor(r0, off);
      r1 += __shfl_xor(r1, off);
      r2 += __shfl_xor(r2, off);
    }
    if (lj < 3) {
      float oo = (lj == 0) ? r0 : (lj == 1) ? r1 : r2;
      vbuf[(size_t)3 * vv + lj] = oo * sc + tr;
    }
    __builtin_amdgcn_sched_barrier(0);
    __builtin_amdgcn_s_barrier();
    __builtin_amdgcn_sched_barrier(0);
  }
  // drain in-flight (dummy) DMA before LDS is deallocated
  asm volatile("s_waitcnt vmcnt(0)" ::: "memory");
}

extern "C" void kernel_launch(void* const* d_in, const int* in_sizes, int n_in,
                              void* d_out, int out_size, void* d_ws, size_t ws_size,
                              hipStream_t stream) {
  const float* betas      = (const float*)d_in[0];
  const float* pose       = (const float*)d_in[1];
  const float* scale      = (const float*)d_in[2];
  const float* trans      = (const float*)d_in[3];
  const float* v_template = (const float*)d_in[4];
  const float* shapedirs  = (const float*)d_in[5];
  const float* posedirs   = (const float*)d_in[6];
  const float* Jreg       = (const float*)d_in[7];
  const float* weights    = (const float*)d_in[8];
  float* out = (float*)d_out;
  float* ws  = (float*)d_ws;

  float* jpart = ws;          // 25*24*3 = 1800 floats
  float* lrot  = ws + 1800;   // 207 floats
  float* rel   = ws + 2048;   // 288 floats

  k_shape<<<(3 * NV + 255) / 256, 256, 0, stream>>>(betas, v_template, shapedirs, out);
  k_jreg<<<dim3(NJ, NPART), 256, 0, stream>>>(Jreg, out, jpart);
  k_fk<<<1, 64, 0, stream>>>(pose, jpart, lrot, rel);
  k_fused<<<GRIDF, 256, 0, stream>>>(posedirs, weights, lrot, rel, scale, trans, out);
}